// Round 3
// baseline (149.759 us; speedup 1.0000x reference)
//
#include <hip/hip_runtime.h>
#include <stdint.h>

// LmHead: RMSNorm(8x4096) -> logits = h @ W^T (W: 32000x4096 f32) -> argmax per row.
// Memory-bound: W is 524 MB (> 256 MiB L3) -> pure HBM read stream, floor ~82us.
// R2: 136us. Diagnosis: (a) in-order vmcnt retirement made per-chunk L2 h-loads
//     wait behind the next chunk's HBM W-prefetch (pipeline defeated);
//     (b) dummy tail prefetch re-read 4KB/group = +6% HBM traffic.
// R3: h staged in 128KB LDS (ds_read -> lgkmcnt, decoupled from W's vmcnt queue);
//     W is the only vmem in the loop (counted-vmcnt ping-pong, never drains);
//     256 persistent blocks x 1024 thr (1 blk/CU, 16 waves), proper tail (no re-read).

#define D 4096
#define BATCH 8
#define VOCAB 32000
#define VT 4                    // vocab rows per wave-group
#define NGROUPS (VOCAB / VT)    // 8000
#define NBLK 256                // 1 block per CU (LDS-capped)
#define WPB 16                  // waves per block
#define NWAVES (NBLK * WPB)     // 4096 -> ~2 groups per wave
#define EPS 1e-6f

typedef unsigned long long u64;
typedef float f32x4 __attribute__((ext_vector_type(4)));

// ---------------- Kernel A: RMSNorm -> h in workspace ----------------
__global__ __launch_bounds__(256) void rmsnorm_k(const float* __restrict__ x,
                                                 const float* __restrict__ g,
                                                 float* __restrict__ h) {
    const int b = blockIdx.x;
    const int t = threadIdx.x;
    const int wave = t >> 6, lane = t & 63;
    const float* xr = x + b * D;

    f32x4 xv[4];
    float s = 0.f;
#pragma unroll
    for (int i = 0; i < 4; ++i) {
        xv[i] = *(const f32x4*)(xr + i * 1024 + t * 4);
        s += xv[i].x * xv[i].x + xv[i].y * xv[i].y + xv[i].z * xv[i].z + xv[i].w * xv[i].w;
    }
#pragma unroll
    for (int m = 1; m < 64; m <<= 1) s += __shfl_xor(s, m, 64);

    __shared__ float wsum[4];
    if (lane == 0) wsum[wave] = s;
    __syncthreads();
    const float tot = wsum[0] + wsum[1] + wsum[2] + wsum[3];
    const float rs = rsqrtf(tot * (1.f / (float)D) + EPS);

#pragma unroll
    for (int i = 0; i < 4; ++i) {
        const int d = i * 1024 + t * 4;
        const f32x4 gv = *(const f32x4*)(g + d);
        f32x4 o;
        o.x = xv[i].x * rs * gv.x;
        o.y = xv[i].y * rs * gv.y;
        o.z = xv[i].z * rs * gv.z;
        o.w = xv[i].w * rs * gv.w;
        *(f32x4*)(h + b * D + d) = o;
    }
}

// ------- Kernel B: LDS-h, W-only vmem ping-pong, per-wave 4-row GEMV+argmax -------
__global__ __launch_bounds__(1024, 4) void gemv_argmax_k(const float* __restrict__ W,
                                                         const float* __restrict__ h,
                                                         u64* __restrict__ partial) {
    extern __shared__ float hs[];   // 8*4096 f32 = 128 KB (dynamic)
    const int t = threadIdx.x;

    // stage h -> LDS once (coalesced f32x4; 8192 vectors / 1024 threads = 8 each)
    {
        const f32x4* src = (const f32x4*)h;
        f32x4* dst = (f32x4*)hs;
#pragma unroll
        for (int i = 0; i < 8; ++i) dst[i * 1024 + t] = src[i * 1024 + t];
    }
    __syncthreads();

    const int lane = t & 63;
    const int wave = t >> 6;
    const int wid = blockIdx.x * WPB + wave;
    const int dl = lane * 4;

    u64 best = 0ull;  // packed (sortable_f32 << 32) | ~idx ; 0 neutral (no NaNs)

    f32x4 bufA[VT], bufB[VT];

#define LOADW(BUF, WB, c)                                                          \
    {                                                                              \
        const int _d = (c) * 256 + dl;                                             \
        _Pragma("unroll")                                                          \
        for (int vi = 0; vi < VT; ++vi)                                            \
            BUF[vi] = __builtin_nontemporal_load((const f32x4*)((WB) + vi * D + _d)); \
    }

#define COMPUTE(BUF, c)                                                            \
    {                                                                              \
        const int _d = (c) * 256 + dl;                                             \
        _Pragma("unroll")                                                          \
        for (int b = 0; b < 8; ++b) {                                              \
            const f32x4 hv = *(const f32x4*)(hs + b * D + _d);                     \
            _Pragma("unroll")                                                      \
            for (int vi = 0; vi < VT; ++vi)                                        \
                acc[b * VT + vi] += BUF[vi].x * hv.x + BUF[vi].y * hv.y +          \
                                    BUF[vi].z * hv.z + BUF[vi].w * hv.w;           \
        }                                                                          \
    }

#pragma unroll 1
    for (int grp = wid; grp < NGROUPS; grp += NWAVES) {
        const float* Wb = W + (size_t)grp * (VT * D);

        float acc[32];
#pragma unroll
        for (int i = 0; i < 32; ++i) acc[i] = 0.f;

        // software pipeline over 16 chunks, each loaded exactly once:
        // prime A(0); {B(c+1) A(c) A(c+2) B(c+1)}*7 ; tail B(15) A(14) B(15)
        LOADW(bufA, Wb, 0)
#pragma unroll 1
        for (int c = 0; c <= 12; c += 2) {
            LOADW(bufB, Wb, c + 1)
            COMPUTE(bufA, c)
            LOADW(bufA, Wb, c + 2)
            COMPUTE(bufB, c + 1)
        }
        // loop exits having loaded A(14) and computed through chunk 13
        LOADW(bufB, Wb, 15)
        COMPUTE(bufA, 14)
        COMPUTE(bufB, 15)

        // Butterfly: 32 partials across 64 lanes -> lane l holds total for
        // j = l&31 (b = j>>2, vi = j&3). All indices compile-time.
#pragma unroll
        for (int s = 0; s < 5; ++s) {
            const int m = 1 << s;
            const bool bit = (lane & m) != 0;
#pragma unroll
            for (int u = 0; u < (32 >> (s + 1)); ++u) {
                const float a = acc[2 * u];
                const float c2 = acc[2 * u + 1];
                const float keep = bit ? c2 : a;
                const float send = bit ? a : c2;
                acc[u] = keep + __shfl_xor(send, m, 64);
            }
        }
        const float logit = acc[0] + __shfl_xor(acc[0], 32, 64);  // fold dup halves

        const int vidx = grp * VT + (lane & 3);
        const uint32_t fb = __float_as_uint(logit);
        const uint32_t key = (fb & 0x80000000u) ? ~fb : (fb | 0x80000000u);
        const u64 pk = ((u64)key << 32) | (uint32_t)(~(uint32_t)vidx);
        if (pk > best) best = pk;
    }
#undef LOADW
#undef COMPUTE

    // merge across vi lanes (bits 0,1); halves already duplicates (bit 5 folded)
#pragma unroll
    for (int m = 1; m <= 2; m <<= 1) {
        const u64 o = __shfl_xor(best, m, 64);
        if (o > best) best = o;
    }
    {
        const u64 o = __shfl_xor(best, 32, 64);
        if (o > best) best = o;
    }

    __shared__ u64 lb[WPB][8];
    if (lane < 32 && (lane & 3) == 0) lb[wave][lane >> 2] = best;
    __syncthreads();
    if (t < 8) {
        u64 m = lb[0][t];
#pragma unroll
        for (int w2 = 1; w2 < WPB; ++w2) {
            const u64 o = lb[w2][t];
            if (o > m) m = o;
        }
        partial[(size_t)blockIdx.x * 8 + t] = m;
    }
}

// ---------------- Kernel C: final argmax over block partials ----------------
__global__ __launch_bounds__(512) void finalize_k(const u64* __restrict__ partial,
                                                  int* __restrict__ out, int nblk) {
    const int b = threadIdx.x >> 6;   // one wave per batch row
    const int lane = threadIdx.x & 63;
    u64 best = 0ull;
    for (int p = lane; p < nblk; p += 64) {
        const u64 x = partial[(size_t)p * 8 + b];
        if (x > best) best = x;
    }
#pragma unroll
    for (int m = 1; m < 64; m <<= 1) {
        const u64 o = __shfl_xor(best, m, 64);
        if (o > best) best = o;
    }
    if (lane == 0) out[b] = (int)(~(uint32_t)best);
}

extern "C" void kernel_launch(void* const* d_in, const int* in_sizes, int n_in,
                              void* d_out, int out_size, void* d_ws, size_t ws_size,
                              hipStream_t stream) {
    const float* x = (const float*)d_in[0]; // hidden_states [8,4096]
    const float* g = (const float*)d_in[1]; // norm_weight [4096]
    const float* W = (const float*)d_in[2]; // lm_head_weight [32000,4096]
    int* out = (int*)d_out;                 // [8] int32 token ids

    float* h = (float*)d_ws;                                        // 128 KB
    u64* partial = (u64*)((char*)d_ws + BATCH * D * sizeof(float)); // 256*8*8B = 16 KB

    rmsnorm_k<<<BATCH, 256, 0, stream>>>(x, g, h);
    gemv_argmax_k<<<NBLK, 1024, BATCH * D * sizeof(float), stream>>>(W, h, partial);
    finalize_k<<<1, 512, 0, stream>>>(partial, out, NBLK);
}

// Round 4
// 125.839 us; speedup vs baseline: 1.1901x; 1.1901x over previous
//
#include <hip/hip_runtime.h>
#include <stdint.h>

// LmHead: RMSNorm(8x4096) -> logits = h @ W^T (W: 32000x4096 f32) -> argmax per row.
// Memory-bound: W is 524 MB (> 256 MiB L3) -> pure HBM read stream, floor ~82us.
// R2 (136us): per-chunk h-loads were the YOUNGEST vmem -> using them forced
//   vmcnt(0), draining the W prefetch queue every chunk (in-order retirement).
// R3 (150us): LDS-h fixed coupling but collapsed occupancy (1 blk/CU). Reverted.
// R4: keep R2's 256-thr/2000-blk shape; double-buffer BOTH h and W in registers
//   with issue-order discipline: phase c issues h(c+1),W(c+1) then computes c
//   whose operands are the oldest outstanding -> compiler emits counted
//   s_waitcnt vmcnt(12); the vmem queue NEVER drains in the 16-chunk loop.

#define D 4096
#define BATCH 8
#define VOCAB 32000
#define VT 4                 // vocab rows per wave
#define NGROUPS (VOCAB / VT) // 8000
#define NBLK 2000            // 4 waves/block -> 8000 waves, exactly 1 group per wave
#define EPS 1e-6f

typedef unsigned long long u64;
typedef float f32x4 __attribute__((ext_vector_type(4)));

// ---------------- Kernel A: RMSNorm -> h in workspace ----------------
__global__ __launch_bounds__(256) void rmsnorm_k(const float* __restrict__ x,
                                                 const float* __restrict__ g,
                                                 float* __restrict__ h) {
    const int b = blockIdx.x;
    const int t = threadIdx.x;
    const int wave = t >> 6, lane = t & 63;
    const float* xr = x + b * D;

    f32x4 xv[4];
    float s = 0.f;
#pragma unroll
    for (int i = 0; i < 4; ++i) {
        xv[i] = *(const f32x4*)(xr + i * 1024 + t * 4);
        s += xv[i].x * xv[i].x + xv[i].y * xv[i].y + xv[i].z * xv[i].z + xv[i].w * xv[i].w;
    }
#pragma unroll
    for (int m = 1; m < 64; m <<= 1) s += __shfl_xor(s, m, 64);

    __shared__ float wsum[4];
    if (lane == 0) wsum[wave] = s;
    __syncthreads();
    const float tot = wsum[0] + wsum[1] + wsum[2] + wsum[3];
    const float rs = rsqrtf(tot * (1.f / (float)D) + EPS);

#pragma unroll
    for (int i = 0; i < 4; ++i) {
        const int d = i * 1024 + t * 4;
        const f32x4 gv = *(const f32x4*)(g + d);
        f32x4 o;
        o.x = xv[i].x * rs * gv.x;
        o.y = xv[i].y * rs * gv.y;
        o.z = xv[i].z * rs * gv.z;
        o.w = xv[i].w * rs * gv.w;
        *(f32x4*)(h + b * D + d) = o;
    }
}

// ---- Kernel B: reg-dbuf (h AND W), counted-vmcnt GEMV + packed argmax ----
__global__ __launch_bounds__(256) void gemv_argmax_k(const float* __restrict__ W,
                                                     const float* __restrict__ h,
                                                     u64* __restrict__ partial) {
    const int lane = threadIdx.x & 63;
    const int wave = threadIdx.x >> 6;
    const int grp = blockIdx.x * 4 + wave;       // [0, 8000)
    const int v0 = grp * VT;
    const float* Wb = W + (size_t)v0 * D;
    const int dl = lane * 4;

    float acc[32];
#pragma unroll
    for (int i = 0; i < 32; ++i) acc[i] = 0.f;

    f32x4 wA[VT], wB[VT];      // W double-buffer (nt: streaming, no L2 alloc)
    f32x4 hA[8], hB[8];        // h double-buffer (L2-hot, cached)

#define LOADH(HB, c)                                                           \
    {                                                                          \
        const int _d = (c) * 256 + dl;                                         \
        _Pragma("unroll")                                                      \
        for (int b = 0; b < 8; ++b)                                            \
            HB[b] = *(const f32x4*)(h + b * D + _d);                           \
    }

#define LOADW(BUF, c)                                                          \
    {                                                                          \
        const int _d = (c) * 256 + dl;                                         \
        _Pragma("unroll")                                                      \
        for (int vi = 0; vi < VT; ++vi)                                        \
            BUF[vi] = __builtin_nontemporal_load((const f32x4*)(Wb + vi * D + _d)); \
    }

#define COMPUTE(HB, WBUF)                                                      \
    {                                                                          \
        _Pragma("unroll")                                                      \
        for (int b = 0; b < 8; ++b) {                                          \
            _Pragma("unroll")                                                  \
            for (int vi = 0; vi < VT; ++vi)                                    \
                acc[b * VT + vi] += WBUF[vi].x * HB[b].x + WBUF[vi].y * HB[b].y + \
                                    WBUF[vi].z * HB[b].z + WBUF[vi].w * HB[b].w;  \
        }                                                                      \
    }

    // prologue: fill A with chunk 0
    LOADH(hA, 0)
    LOADW(wA, 0)
    // steady state: issue next chunk's 12 loads, then compute current (oldest)
#pragma unroll 1
    for (int c = 0; c <= 12; c += 2) {
        LOADH(hB, c + 1)
        LOADW(wB, c + 1)
        COMPUTE(hA, wA)        // waits vmcnt(12) — counted, no drain
        LOADH(hA, c + 2)       // c+2 <= 14
        LOADW(wA, c + 2)
        COMPUTE(hB, wB)
    }
    // loop exit: computed through chunk 13; chunk 14 resident in A
    LOADH(hB, 15)
    LOADW(wB, 15)
    COMPUTE(hA, wA)
    COMPUTE(hB, wB)
#undef LOADH
#undef LOADW
#undef COMPUTE

    // Butterfly: 32 partials across 64 lanes -> lane l holds total for
    // j = l&31 (b = j>>2, vi = j&3). All indices compile-time.
#pragma unroll
    for (int s = 0; s < 5; ++s) {
        const int m = 1 << s;
        const bool bit = (lane & m) != 0;
#pragma unroll
        for (int u = 0; u < (32 >> (s + 1)); ++u) {
            const float a = acc[2 * u];
            const float c2 = acc[2 * u + 1];
            const float keep = bit ? c2 : a;
            const float send = bit ? a : c2;
            acc[u] = keep + __shfl_xor(send, m, 64);
        }
    }
    const float logit = acc[0] + __shfl_xor(acc[0], 32, 64);  // fold dup halves

    const int vidx = v0 + (lane & 3);
    const uint32_t fb = __float_as_uint(logit);
    const uint32_t key = (fb & 0x80000000u) ? ~fb : (fb | 0x80000000u);
    u64 best = ((u64)key << 32) | (uint32_t)(~(uint32_t)vidx);

    // merge across vi (bits 0,1); halves are duplicates after the fold
#pragma unroll
    for (int m = 1; m <= 2; m <<= 1) {
        const u64 o = __shfl_xor(best, m, 64);
        if (o > best) best = o;
    }
    {
        const u64 o = __shfl_xor(best, 32, 64);
        if (o > best) best = o;
    }

    __shared__ u64 lb[4][8];
    if (lane < 32 && (lane & 3) == 0) lb[wave][lane >> 2] = best;
    __syncthreads();
    if (threadIdx.x < 8) {
        const u64 m0 = lb[0][threadIdx.x], m1 = lb[1][threadIdx.x];
        const u64 m2 = lb[2][threadIdx.x], m3 = lb[3][threadIdx.x];
        const u64 a = m0 > m1 ? m0 : m1;
        const u64 b2 = m2 > m3 ? m2 : m3;
        partial[(size_t)blockIdx.x * 8 + threadIdx.x] = a > b2 ? a : b2;
    }
}

// ---------------- Kernel C: final argmax over block partials ----------------
__global__ __launch_bounds__(512) void finalize_k(const u64* __restrict__ partial,
                                                  int* __restrict__ out, int nblk) {
    const int b = threadIdx.x >> 6;   // one wave per batch row
    const int lane = threadIdx.x & 63;
    u64 best = 0ull;
    for (int p = lane; p < nblk; p += 64) {
        const u64 x = partial[(size_t)p * 8 + b];
        if (x > best) best = x;
    }
#pragma unroll
    for (int m = 1; m < 64; m <<= 1) {
        const u64 o = __shfl_xor(best, m, 64);
        if (o > best) best = o;
    }
    if (lane == 0) out[b] = (int)(~(uint32_t)best);
}

extern "C" void kernel_launch(void* const* d_in, const int* in_sizes, int n_in,
                              void* d_out, int out_size, void* d_ws, size_t ws_size,
                              hipStream_t stream) {
    const float* x = (const float*)d_in[0]; // hidden_states [8,4096]
    const float* g = (const float*)d_in[1]; // norm_weight [4096]
    const float* W = (const float*)d_in[2]; // lm_head_weight [32000,4096]
    int* out = (int*)d_out;                 // [8] int32 token ids

    float* h = (float*)d_ws;                                        // 128 KB
    u64* partial = (u64*)((char*)d_ws + BATCH * D * sizeof(float)); // 2000*8*8B

    rmsnorm_k<<<BATCH, 256, 0, stream>>>(x, g, h);
    gemv_argmax_k<<<NBLK, 256, 0, stream>>>(W, h, partial);
    finalize_k<<<1, 512, 0, stream>>>(partial, out, NBLK);
}